// Round 1
// baseline (352.411 us; speedup 1.0000x reference)
//
#include <hip/hip_runtime.h>

#define BATCH 16384
#define SEQ 512

__device__ __forceinline__ float fast_sig(float v) {
    // 1/(1+exp(-v)) ; exp2-based, saturates correctly at +-inf
    float e = __builtin_amdgcn_exp2f(v * -1.44269504088896f);
    return __builtin_amdgcn_rcpf(1.0f + e);
}
__device__ __forceinline__ float fast_tanh(float v) {
    // 2/(1+exp(-2v)) - 1
    float e = __builtin_amdgcn_exp2f(v * -2.88539008177793f);
    return fmaf(2.0f, __builtin_amdgcn_rcpf(1.0f + e), -1.0f);
}
__device__ __forceinline__ float bperm(int byte_addr, float v) {
    return __int_as_float(__builtin_amdgcn_ds_bpermute(byte_addr, __float_as_int(v)));
}

// ws[0..2559] = Wc = W2 @ W1  (collapsed MLP: no nonlinearity between W1 and W2)
// ws[2560]    = cbias = W2 . b1 + b2
__global__ __launch_bounds__(256, 1) void collapse_kernel(
    const float* __restrict__ W1, const float* __restrict__ b1,
    const float* __restrict__ W2, const float* __restrict__ b2,
    float* __restrict__ ws)
{
    const int kl = threadIdx.x & 31;   // k within block (32 columns/block)
    const int ms = threadIdx.x >> 5;   // m-slice 0..7 (64 rows each)
    const int k  = blockIdx.x * 32 + kl;
    const float* w1p = W1 + (size_t)(ms * 64) * 2560 + k;
    const float* w2p = W2 + ms * 64;
    float acc = 0.f;
    #pragma unroll 8
    for (int m = 0; m < 64; ++m) acc = fmaf(w2p[m], w1p[(size_t)m * 2560], acc);
    __shared__ float red[8][33];
    red[ms][kl] = acc;
    __syncthreads();
    if (ms == 0) {
        float s = 0.f;
        #pragma unroll
        for (int r = 0; r < 8; ++r) s += red[r][kl];
        ws[k] = s;
    }
    if (blockIdx.x == 0) {
        const int t = threadIdx.x;
        float p = fmaf(W2[t], b1[t], W2[t + 256] * b1[t + 256]);
        #pragma unroll
        for (int off = 32; off > 0; off >>= 1) p += __shfl_down(p, off);
        __shared__ float cred[4];
        if ((t & 63) == 0) cred[t >> 6] = p;
        __syncthreads();
        if (t == 0) ws[2560] = cred[0] + cred[1] + cred[2] + cred[3] + b2[0];
    }
}

// Unit-split LSTM: 5 lanes per batch element, lane j owns hidden unit j of both
// layers (all 4 gates + c state + activations local to the lane). Only cross-lane
// op is the 5-wide h broadcast (ds_bpermute) per layer-step. 12 elements per wave
// (lanes 60-63 idle). MLP head fused as running dot with collapsed Wc.
__global__ __launch_bounds__(256, 1) void lstm_fused_kernel(
    const float* __restrict__ x,
    const float* __restrict__ Wih0, const float* __restrict__ Whh0,
    const float* __restrict__ bih0, const float* __restrict__ bhh0,
    const float* __restrict__ Wih1, const float* __restrict__ Whh1,
    const float* __restrict__ bih1, const float* __restrict__ bhh1,
    const float* __restrict__ ws, float* __restrict__ out)
{
    const int lane = threadIdx.x & 63;
    const int wv   = threadIdx.x >> 6;
    const int g    = lane / 5;          // group (element slot) in wave, 0..11; 12 = idle lanes
    const int j    = lane - g * 5;      // hidden unit 0..4
    const int e    = blockIdx.x * 48 + wv * 12 + g;
    const bool live = (g < 12) && (e < BATCH);
    const int ec   = min(e, BATCH - 1);
    const int base = g * 5;
    const int a0 = (base + 0) << 2, a1 = (base + 1) << 2, a2 = (base + 2) << 2,
              a3 = (base + 3) << 2, a4 = (base + 4) << 2;

    // per-lane weights: rows gate*5 + j (PyTorch gate order i,f,g,o)
    float wih0v[4], bb0[4], whh0v[4][5], wih1v[4][5], bb1[4], whh1v[4][5];
    #pragma unroll
    for (int gg = 0; gg < 4; ++gg) {
        const int r = gg * 5 + j;
        wih0v[gg] = Wih0[r];
        bb0[gg] = bih0[r] + bhh0[r];
        bb1[gg] = bih1[r] + bhh1[r];
        #pragma unroll
        for (int k = 0; k < 5; ++k) {
            whh0v[gg][k] = Whh0[r * 5 + k];
            wih1v[gg][k] = Wih1[r * 5 + k];
            whh1v[gg][k] = Whh1[r * 5 + k];
        }
    }

    float h0[5] = {0, 0, 0, 0, 0}, h1[5] = {0, 0, 0, 0, 0};
    float c0 = 0.f, c1 = 0.f, acc = 0.f;
    const float* xp  = x + (size_t)ec * SEQ;
    const float* wcp = ws + j;          // Wc[t*5 + j] = wcp[5t]

    float4 xb = *(const float4*)xp;
    float wcb0 = wcp[0], wcb1 = wcp[5], wcb2 = wcp[10], wcb3 = wcp[15];

    for (int t = 0; t < SEQ; t += 4) {
        // prefetch next 4 steps (wrap at end; covered by ~4 steps of compute)
        const int tn = (t + 4) & (SEQ - 1);
        float4 xn = *(const float4*)(xp + tn);
        const int tb = tn * 5;
        float wn0 = wcp[tb], wn1 = wcp[tb + 5], wn2 = wcp[tb + 10], wn3 = wcp[tb + 15];

        const float xv[4] = {xb.x, xb.y, xb.z, xb.w};
        const float wc_[4] = {wcb0, wcb1, wcb2, wcb3};
        #pragma unroll
        for (int u = 0; u < 4; ++u) {
            // ---------- layer 0 ----------
            float p0 = fmaf(xv[u], wih0v[0], bb0[0]);
            float p1 = fmaf(xv[u], wih0v[1], bb0[1]);
            float p2 = fmaf(xv[u], wih0v[2], bb0[2]);
            float p3 = fmaf(xv[u], wih0v[3], bb0[3]);
            #pragma unroll
            for (int k = 0; k < 5; ++k) {
                p0 = fmaf(whh0v[0][k], h0[k], p0);
                p1 = fmaf(whh0v[1][k], h0[k], p1);
                p2 = fmaf(whh0v[2][k], h0[k], p2);
                p3 = fmaf(whh0v[3][k], h0[k], p3);
            }
            float i0 = fast_sig(p0), f0 = fast_sig(p1);
            float g0 = fast_tanh(p2), o0 = fast_sig(p3);
            c0 = fmaf(f0, c0, i0 * g0);
            float hj0 = o0 * fast_tanh(c0);
            h0[0] = bperm(a0, hj0); h0[1] = bperm(a1, hj0); h0[2] = bperm(a2, hj0);
            h0[3] = bperm(a3, hj0); h0[4] = bperm(a4, hj0);
            // ---------- layer 1 ----------
            float q0 = bb1[0], q1 = bb1[1], q2 = bb1[2], q3 = bb1[3];
            #pragma unroll
            for (int k = 0; k < 5; ++k) {
                q0 = fmaf(wih1v[0][k], h0[k], q0);
                q1 = fmaf(wih1v[1][k], h0[k], q1);
                q2 = fmaf(wih1v[2][k], h0[k], q2);
                q3 = fmaf(wih1v[3][k], h0[k], q3);
            }
            #pragma unroll
            for (int k = 0; k < 5; ++k) {
                q0 = fmaf(whh1v[0][k], h1[k], q0);
                q1 = fmaf(whh1v[1][k], h1[k], q1);
                q2 = fmaf(whh1v[2][k], h1[k], q2);
                q3 = fmaf(whh1v[3][k], h1[k], q3);
            }
            float i1 = fast_sig(q0), f1 = fast_sig(q1);
            float g1 = fast_tanh(q2), o1 = fast_sig(q3);
            c1 = fmaf(f1, c1, i1 * g1);
            float hj1 = o1 * fast_tanh(c1);
            h1[0] = bperm(a0, hj1); h1[1] = bperm(a1, hj1); h1[2] = bperm(a2, hj1);
            h1[3] = bperm(a3, hj1); h1[4] = bperm(a4, hj1);
            // fused MLP head: acc_j += h1_j(t) * Wc[t*5+j]
            acc = fmaf(hj1, wc_[u], acc);
        }
        xb = xn;
        wcb0 = wn0; wcb1 = wn1; wcb2 = wn2; wcb3 = wn3;
    }

    // reduce the 5 per-unit partial dots within the group
    float t0 = bperm(a0, acc), t1 = bperm(a1, acc), t2 = bperm(a2, acc),
          t3 = bperm(a3, acc), t4 = bperm(a4, acc);
    float total = ((t0 + t1) + (t2 + t3)) + t4;
    if (live && j == 0) out[e] = total + ws[2560];
}

extern "C" void kernel_launch(void* const* d_in, const int* in_sizes, int n_in,
                              void* d_out, int out_size, void* d_ws, size_t ws_size,
                              hipStream_t stream) {
    const float* x    = (const float*)d_in[0];
    const float* Wih0 = (const float*)d_in[1];
    const float* Whh0 = (const float*)d_in[2];
    const float* bih0 = (const float*)d_in[3];
    const float* bhh0 = (const float*)d_in[4];
    const float* Wih1 = (const float*)d_in[5];
    const float* Whh1 = (const float*)d_in[6];
    const float* bih1 = (const float*)d_in[7];
    const float* bhh1 = (const float*)d_in[8];
    const float* W1   = (const float*)d_in[9];
    const float* b1   = (const float*)d_in[10];
    const float* W2   = (const float*)d_in[11];
    const float* b2   = (const float*)d_in[12];
    float* out = (float*)d_out;
    float* ws  = (float*)d_ws;

    collapse_kernel<<<80, 256, 0, stream>>>(W1, b1, W2, b2, ws);
    const int grid = (BATCH + 47) / 48;  // 342 blocks, 48 elements each
    lstm_fused_kernel<<<grid, 256, 0, stream>>>(x, Wih0, Whh0, bih0, bhh0,
                                                Wih1, Whh1, bih1, bhh1, ws, out);
}

// Round 2
// 320.666 us; speedup vs baseline: 1.0990x; 1.0990x over previous
//
#include <hip/hip_runtime.h>

#define BATCH 16384
#define SEQ 512

typedef float v2f __attribute__((ext_vector_type(2)));

__device__ __forceinline__ float fast_sig(float v) {
    // 1/(1+exp(-v)) via exp2; saturates correctly at +-inf
    float e = __builtin_amdgcn_exp2f(v * -1.44269504088896f);
    return __builtin_amdgcn_rcpf(1.0f + e);
}
__device__ __forceinline__ float fast_tanh(float v) {
    // 2/(1+exp(-2v)) - 1
    float e = __builtin_amdgcn_exp2f(v * -2.88539008177793f);
    return fmaf(2.0f, __builtin_amdgcn_rcpf(1.0f + e), -1.0f);
}
__device__ __forceinline__ float bperm(int byte_addr, float v) {
    return __int_as_float(__builtin_amdgcn_ds_bpermute(byte_addr, __float_as_int(v)));
}
__device__ __forceinline__ v2f splat(float v) { return (v2f){v, v}; }

// ws[0..2559] = Wc = W2 @ W1  (collapsed MLP: no nonlinearity between W1 and W2)
// ws[2560]    = cbias = W2 . b1 + b2
__global__ __launch_bounds__(256, 1) void collapse_kernel(
    const float* __restrict__ W1, const float* __restrict__ b1,
    const float* __restrict__ W2, const float* __restrict__ b2,
    float* __restrict__ ws)
{
    const int kl = threadIdx.x & 31;   // k within block (32 columns/block)
    const int ms = threadIdx.x >> 5;   // m-slice 0..7 (64 rows each)
    const int k  = blockIdx.x * 32 + kl;
    const float* w1p = W1 + (size_t)(ms * 64) * 2560 + k;
    const float* w2p = W2 + ms * 64;
    float acc = 0.f;
    #pragma unroll 8
    for (int m = 0; m < 64; ++m) acc = fmaf(w2p[m], w1p[(size_t)m * 2560], acc);
    __shared__ float red[8][33];
    red[ms][kl] = acc;
    __syncthreads();
    if (ms == 0) {
        float s = 0.f;
        #pragma unroll
        for (int r = 0; r < 8; ++r) s += red[r][kl];
        ws[k] = s;
    }
    if (blockIdx.x == 0) {
        const int t = threadIdx.x;
        float p = fmaf(W2[t], b1[t], W2[t + 256] * b1[t + 256]);
        #pragma unroll
        for (int off = 32; off > 0; off >>= 1) p += __shfl_down(p, off);
        __shared__ float cred[4];
        if ((t & 63) == 0) cred[t >> 6] = p;
        __syncthreads();
        if (t == 0) ws[2560] = cred[0] + cred[1] + cred[2] + cred[3] + b2[0];
    }
}

// Unit-split LSTM, software-pipelined: 5 lanes per batch element, lane j owns
// hidden unit j of both layers. Layer0 for step t+1 is computed alongside
// layer1 for step t (both consume h0(t)), so the two ds_bpermute broadcast
// latencies overlap with independent ALU work. Gate pairs (i,f)/(g,o) are
// float2 -> v_pk_fma_f32. amdgpu_waves_per_eu(1,2) keeps the ~72 weight
// regs resident (round-1's VGPR=64 allocation spilled them into the loop).
__global__ __launch_bounds__(64)
__attribute__((amdgpu_waves_per_eu(1, 2)))
void lstm_fused_kernel(
    const float* __restrict__ x,
    const float* __restrict__ Wih0, const float* __restrict__ Whh0,
    const float* __restrict__ bih0, const float* __restrict__ bhh0,
    const float* __restrict__ Wih1, const float* __restrict__ Whh1,
    const float* __restrict__ bih1, const float* __restrict__ bhh1,
    const float* __restrict__ ws, float* __restrict__ out)
{
    const int lane = threadIdx.x;       // block = 1 wave
    const int g    = lane / 5;          // element slot 0..11 (12 = idle lanes)
    const int j    = lane - g * 5;      // hidden unit 0..4
    const int e    = blockIdx.x * 12 + g;
    const bool live = (g < 12) && (e < BATCH);
    const int ec   = min(e, BATCH - 1);
    const int base = g * 5;
    const int a0 = (base + 0) << 2, a1 = (base + 1) << 2, a2 = (base + 2) << 2,
              a3 = (base + 3) << 2, a4 = (base + 4) << 2;

    // per-lane weights as gate-pair float2: .x = gate i (or g), .y = gate f (or o)
    v2f wih0_01, wih0_23, bb0_01, bb0_23, bb1_01, bb1_23;
    v2f whh0_01[5], whh0_23[5], wih1_01[5], wih1_23[5], whh1_01[5], whh1_23[5];
    {
        const int r0 = 0 + j, r1 = 5 + j, r2 = 10 + j, r3 = 15 + j;
        wih0_01 = (v2f){Wih0[r0], Wih0[r1]};
        wih0_23 = (v2f){Wih0[r2], Wih0[r3]};
        bb0_01  = (v2f){bih0[r0] + bhh0[r0], bih0[r1] + bhh0[r1]};
        bb0_23  = (v2f){bih0[r2] + bhh0[r2], bih0[r3] + bhh0[r3]};
        bb1_01  = (v2f){bih1[r0] + bhh1[r0], bih1[r1] + bhh1[r1]};
        bb1_23  = (v2f){bih1[r2] + bhh1[r2], bih1[r3] + bhh1[r3]};
        #pragma unroll
        for (int k = 0; k < 5; ++k) {
            whh0_01[k] = (v2f){Whh0[r0 * 5 + k], Whh0[r1 * 5 + k]};
            whh0_23[k] = (v2f){Whh0[r2 * 5 + k], Whh0[r3 * 5 + k]};
            wih1_01[k] = (v2f){Wih1[r0 * 5 + k], Wih1[r1 * 5 + k]};
            wih1_23[k] = (v2f){Wih1[r2 * 5 + k], Wih1[r3 * 5 + k]};
            whh1_01[k] = (v2f){Whh1[r0 * 5 + k], Whh1[r1 * 5 + k]};
            whh1_23[k] = (v2f){Whh1[r2 * 5 + k], Whh1[r3 * 5 + k]};
        }
    }

    float h0b[5], h1b[5] = {0, 0, 0, 0, 0};
    float c0, c1 = 0.f, acc = 0.f;
    const float* xp  = x + (size_t)ec * SEQ;
    const float* wcp = ws + j;          // Wc[t*5 + j] = wcp[5t]

    float4 xb = *(const float4*)xp;     // x[0..3]
    float wc0 = wcp[0], wc1 = wcp[5], wc2 = wcp[10], wc3 = wcp[15];

    // prologue: layer0 at t=0 (h0 = c0 = 0)
    {
        float i0 = fast_sig (fmaf(xb.x, wih0_01.x, bb0_01.x));
        float g0 = fast_tanh(fmaf(xb.x, wih0_23.x, bb0_23.x));
        float o0 = fast_sig (fmaf(xb.x, wih0_23.y, bb0_23.y));
        c0 = i0 * g0;
        float hj0 = o0 * fast_tanh(c0);
        h0b[0] = bperm(a0, hj0); h0b[1] = bperm(a1, hj0); h0b[2] = bperm(a2, hj0);
        h0b[3] = bperm(a3, hj0); h0b[4] = bperm(a4, hj0);
    }

    for (int tb = 0; tb < SEQ; tb += 4) {
        const int tn = (tb + 4) & (SEQ - 1);          // wraps on last block
        float4 xn = *(const float4*)(xp + tn);        // x[tb+4 .. tb+7]
        const int wb = tn * 5;
        float wn0 = wcp[wb], wn1 = wcp[wb + 5], wn2 = wcp[wb + 10], wn3 = wcp[wb + 15];

        const float xnx[4] = {xb.y, xb.z, xb.w, xn.x};   // x[t+1] for u=0..3
        const float wcc[4] = {wc0, wc1, wc2, wc3};       // Wc at t for u=0..3
        #pragma unroll
        for (int u = 0; u < 4; ++u) {
            // ---- layer1 gates at step t (uses h0b = h0(t), h1b = h1(t-1)) ----
            v2f Qa01 = bb1_01, Qa23 = bb1_23;
            #pragma unroll
            for (int k = 0; k < 5; ++k) {
                v2f h = splat(h0b[k]);
                Qa01 = wih1_01[k] * h + Qa01;
                Qa23 = wih1_23[k] * h + Qa23;
            }
            v2f Qb01 = whh1_01[0] * splat(h1b[0]);
            v2f Qb23 = whh1_23[0] * splat(h1b[0]);
            #pragma unroll
            for (int k = 1; k < 5; ++k) {
                v2f h = splat(h1b[k]);
                Qb01 = whh1_01[k] * h + Qb01;
                Qb23 = whh1_23[k] * h + Qb23;
            }
            v2f Q01 = Qa01 + Qb01, Q23 = Qa23 + Qb23;
            // ---- layer0 gates at step t+1 (uses same h0b) ----
            v2f xs = splat(xnx[u]);
            v2f P01 = wih0_01 * xs + bb0_01;
            v2f P23 = wih0_23 * xs + bb0_23;
            #pragma unroll
            for (int k = 0; k < 5; ++k) {
                v2f h = splat(h0b[k]);
                P01 = whh0_01[k] * h + P01;
                P23 = whh0_23[k] * h + P23;
            }
            // ---- layer1 activations / state / head ----
            float i1 = fast_sig(Q01.x), f1 = fast_sig(Q01.y);
            float g1 = fast_tanh(Q23.x), o1 = fast_sig(Q23.y);
            c1 = fmaf(f1, c1, i1 * g1);
            float hj1 = o1 * fast_tanh(c1);
            acc = fmaf(hj1, wcc[u], acc);
            // ---- layer0 activations / state ----
            float i0 = fast_sig(P01.x), f0 = fast_sig(P01.y);
            float g0 = fast_tanh(P23.x), o0 = fast_sig(P23.y);
            c0 = fmaf(f0, c0, i0 * g0);
            float hj0 = o0 * fast_tanh(c0);
            // ---- broadcasts (two independent bperm groups; latencies overlap
            //      with the next iteration's gate FMA chains) ----
            h1b[0] = bperm(a0, hj1); h1b[1] = bperm(a1, hj1); h1b[2] = bperm(a2, hj1);
            h1b[3] = bperm(a3, hj1); h1b[4] = bperm(a4, hj1);
            h0b[0] = bperm(a0, hj0); h0b[1] = bperm(a1, hj0); h0b[2] = bperm(a2, hj0);
            h0b[3] = bperm(a3, hj0); h0b[4] = bperm(a4, hj0);
        }
        xb = xn;
        wc0 = wn0; wc1 = wn1; wc2 = wn2; wc3 = wn3;
    }

    // reduce the 5 per-unit partial dots within the group
    float t0 = bperm(a0, acc), t1 = bperm(a1, acc), t2 = bperm(a2, acc),
          t3 = bperm(a3, acc), t4 = bperm(a4, acc);
    float total = ((t0 + t1) + (t2 + t3)) + t4;
    if (live && j == 0) out[e] = total + ws[2560];
}

extern "C" void kernel_launch(void* const* d_in, const int* in_sizes, int n_in,
                              void* d_out, int out_size, void* d_ws, size_t ws_size,
                              hipStream_t stream) {
    const float* x    = (const float*)d_in[0];
    const float* Wih0 = (const float*)d_in[1];
    const float* Whh0 = (const float*)d_in[2];
    const float* bih0 = (const float*)d_in[3];
    const float* bhh0 = (const float*)d_in[4];
    const float* Wih1 = (const float*)d_in[5];
    const float* Whh1 = (const float*)d_in[6];
    const float* bih1 = (const float*)d_in[7];
    const float* bhh1 = (const float*)d_in[8];
    const float* W1   = (const float*)d_in[9];
    const float* b1   = (const float*)d_in[10];
    const float* W2   = (const float*)d_in[11];
    const float* b2   = (const float*)d_in[12];
    float* out = (float*)d_out;
    float* ws  = (float*)d_ws;

    collapse_kernel<<<80, 256, 0, stream>>>(W1, b1, W2, b2, ws);
    const int grid = (BATCH + 11) / 12;  // 1366 blocks, 12 elements each, 1 wave/block
    lstm_fused_kernel<<<grid, 64, 0, stream>>>(x, Wih0, Whh0, bih0, bhh0,
                                               Wih1, Whh1, bih1, bhh1, ws, out);
}